// Round 16
// baseline (680.495 us; speedup 1.0000x reference)
//
#include <hip/hip_runtime.h>
#include <hip/hip_bf16.h>

// MonetMoVDE: B=4 T=2048 D=2048 H=8 E=512 M=8, F=4096, HALF=1024
#define TOK   8192   // B*T
#define DD    2048
#define FF    4096
#define EE    512
#define HALF  1024
#define KCAT  8704   // F + F + E  (concat K for V-GEMMs, 8704 = 272*32)

typedef __bf16 bf16x8 __attribute__((ext_vector_type(8)));
typedef __bf16 bf16x4 __attribute__((ext_vector_type(4)));
typedef float  f32x4  __attribute__((ext_vector_type(4)));
using bf16 = __hip_bfloat16;

#define AS1(p) ((const __attribute__((address_space(1))) void*)(p))
#define AS3(p) ((__attribute__((address_space(3))) void*)(p))

// ---------------- prep: x/u1/u2 f32->bf16 cvt only ----------------
#define PR0 4194304u
#define PR1 6291456u
#define PR2 8388608u
__global__ __launch_bounds__(256)
void prep_cvt(const float* __restrict__ x, const float* __restrict__ u1_w,
              const float* __restrict__ u2_w,
              bf16* __restrict__ Xb, bf16* __restrict__ U1b, bf16* __restrict__ U2b)
{
    const unsigned stride = gridDim.x * blockDim.x;
    for (unsigned i = blockIdx.x * blockDim.x + threadIdx.x; i < PR2; i += stride) {
        const float* src; bf16* dst; unsigned s;
        if (i < PR0)      { s = i;        src = x;    dst = Xb;  }
        else if (i < PR1) { s = i - PR0;  src = u1_w; dst = U1b; }
        else              { s = i - PR1;  src = u2_w; dst = U2b; }
        float4 v = ((const float4*)src)[s];
        bf16x4 o;
        o[0] = (__bf16)v.x; o[1] = (__bf16)v.y; o[2] = (__bf16)v.z; o[3] = (__bf16)v.w;
        ((bf16x4*)dst)[s] = o;
    }
}

// ---------------- GEMM: C[m,n] = sum_k A[m,k] * Bw[n,k] ----------------
// DEEP-PREFETCH variant: BK=32, 4-buffer ring (4 x 32KB), 2 phases/tile,
// stage tile t+3 during tile t -> issue->gate distance = 4 phases (~1300cyc)
// > HBM miss latency (~900cyc). Same rates as r6 per 64-K: 4 barriers,
// 2 gates, 24 ds_reads, 8 stage loads. Buffer = A plane 16KB @0 + B plane
// 16KB @16K; plane = 256 rows x 64B, swizzle byte ^= (((row>>1)&3)<<4)
// (proven zero-conflict). Register-pipelined: ph0 reads afHi(t), MFMA
// fi0-3; ph1 reads afLo/bv(t+1), MFMA fi4-7. bv double-set by parity.
// Ledger: steady gate vmcnt(8) at ph1 retires exactly tile t+1's 4 loads
// (12 outstanding -> 8); tail 8->vmcnt(4)->vmcnt(0). Never drains mid-loop.
// 8 waves (2Mx4N), 16x16x32 MFMA, per-wave C 128x64. Fence-min barriers,
// no setprio. MODE 1 carries 256 piggyback pack blocks (LDS-free).
// Fused dual-GEMM; MODE 0: fp32 store, MODE 1: relu(z+bias)^2 -> bf16 store.
template<int MODE>
__global__ __launch_bounds__(512, 2)
void gemmD(const bf16* __restrict__ A0, const bf16* __restrict__ B0,
           const float* __restrict__ bias0, void* __restrict__ C0,
           const bf16* __restrict__ A1, const bf16* __restrict__ B1,
           const float* __restrict__ bias1, void* __restrict__ C1,
           int nbm, int nbn, int K, int ldc,
           const float* __restrict__ xv11, const float* __restrict__ xv12,
           const float* __restrict__ xv21, const float* __restrict__ xv22,
           const float* __restrict__ xb1, const float* __restrict__ xb2,
           bf16* __restrict__ xWl, bf16* __restrict__ xWr)
{
    __shared__ __align__(16) char smem[131072];   // 4 x 32KB ring
    const int tid  = threadIdx.x;
    const int npg  = nbm * nbn;

    if (MODE == 1 && blockIdx.x >= (unsigned)(2 * npg)) {
        // ---- piggyback pack block (no LDS, no barriers) ----
        const unsigned lane_g = (blockIdx.x - 2 * npg) * 512u + tid;   // [0, 131072)
        #pragma unroll 4
        for (int k = 0; k < 32; ++k) {                                  // 4,194,304 float4 slots
            unsigned w = lane_g + (unsigned)k * 131072u;
            const bool left = w < 2097152u;
            unsigned s = left ? w : w - 2097152u;
            unsigned n = s >> 11, j = s & 2047u;
            const float* vs = left ? (j < 1024u ? xv11 : xv12) : (j < 1024u ? xv21 : xv22);
            unsigned jj = (j < 1024u) ? j : (j - 1024u);
            float4 v = *(const float4*)(vs + (size_t)n * FF + jj * 4);
            bf16x4 o;
            o[0] = (__bf16)v.x; o[1] = (__bf16)v.y; o[2] = (__bf16)v.z; o[3] = (__bf16)v.w;
            bf16* wb = left ? xWl : xWr;
            *(bf16x4*)(wb + (size_t)n * KCAT + ((j < 1024u) ? 0 : FF) + jj * 4) = o;
        }
        #pragma unroll 2
        for (int k = 0; k < 8; ++k) {                                   // 1,048,576 bmat scalars
            unsigned w = lane_g + (unsigned)k * 131072u;
            const bool left = w < 524288u;
            unsigned r = left ? w : w - 524288u;
            unsigned n = r >> 9, e = r & 511u;
            const float* bm = left ? xb1 : xb2;
            bf16* wb = left ? xWl : xWr;
            wb[(size_t)n * KCAT + 2 * FF + e] = __float2bfloat16(bm[(size_t)e * HALF + n]);
        }
        return;
    }

    const int lane = tid & 63;
    const int wid  = tid >> 6;
    const int wm = wid >> 2, wn = wid & 3;
    const int r16 = lane & 15, kb = lane >> 4;

    int bid = blockIdx.x;
    {   // bijective XCD swizzle (m204) over the GEMM blocks only
        int nwg = 2 * npg;
        int q = nwg >> 3, r = nwg & 7;
        int xcd = bid & 7, idx = bid >> 3;
        bid = (xcd < r ? xcd * (q + 1) : r * (q + 1) + (xcd - r) * q) + idx;
    }
    const int g   = bid / npg;
    const int lb  = bid - g * npg;
    const int bm = lb / nbn, bn = lb - bm * nbn;

    const bf16*  A    = g ? A1 : A0;
    const bf16*  Bw   = g ? B1 : B0;
    const float* bias = g ? bias1 : bias0;
    char* Cout = (char*)(g ? C1 : C0);

    const long row0 = (long)bm * 256;
    const int  col0 = bn * 256;
    const int  nt   = K >> 5;             // BK=32 tiles (nt even: 64 / 272)

    // staging sources (pre-swizzled; involution) + linear LDS dest offset
    const char* gA[2]; const char* gB[2];
    #pragma unroll
    for (int l = 0; l < 2; ++l) {
        const uint32_t S = (uint32_t)(l * 512 + tid) * 16;   // byte slot in 16KB plane
        const int r  = (int)(S >> 6);                        // plane row 0..255
        const int cb = (int)((S & 63) ^ ((uint32_t)((r >> 1) & 3) << 4));
        gA[l] = (const char*)A  + (row0 + r) * (long)K * 2 + cb;
        gB[l] = (const char*)Bw + (long)(col0 + r) * K * 2 + cb;
    }
    const uint32_t ldst = (uint32_t)(tid & ~63) * 16;        // 0..8176 within half-plane

    // per-lane read base offsets within a plane (swizzled; proven zero-conflict)
    const uint32_t swz  = ((uint32_t)(r16 >> 1) & 3u) << 4;
    const uint32_t aoff = (uint32_t)((wm * 128 + r16) * 64 + kb * 16) ^ swz;  // + fi*1024 (fi 0..7)
    const uint32_t boff = (uint32_t)((wn * 64  + r16) * 64 + kb * 16) ^ swz;  // + fj*1024 (fj 0..3)

    f32x4 acc[8][4];
    #pragma unroll
    for (int i = 0; i < 8; ++i)
        #pragma unroll
        for (int j = 0; j < 4; ++j)
            acc[i][j] = (f32x4){0.f, 0.f, 0.f, 0.f};

    // stage one tile's A plane / B plane (2 loads each) into ring buffer BUF
#define ST_A(BUF, KO)                                                                     \
    __builtin_amdgcn_global_load_lds(AS1(gA[0] + (KO)), AS3(smem + (BUF) +     0 + ldst), 16, 0, 0); \
    __builtin_amdgcn_global_load_lds(AS1(gA[1] + (KO)), AS3(smem + (BUF) +  8192 + ldst), 16, 0, 0);
#define ST_B(BUF, KO)                                                                     \
    __builtin_amdgcn_global_load_lds(AS1(gB[0] + (KO)), AS3(smem + (BUF) + 16384 + ldst), 16, 0, 0); \
    __builtin_amdgcn_global_load_lds(AS1(gB[1] + (KO)), AS3(smem + (BUF) + 24576 + ldst), 16, 0, 0);

#define MFMA16(AF, BV, IH)                                                                \
    _Pragma("unroll")                                                                     \
    for (int fi = 0; fi < 4; ++fi) {                                                      \
        acc[(IH)*4+fi][0] = __builtin_amdgcn_mfma_f32_16x16x32_bf16(AF[fi], BV[0], acc[(IH)*4+fi][0], 0, 0, 0); \
        acc[(IH)*4+fi][1] = __builtin_amdgcn_mfma_f32_16x16x32_bf16(AF[fi], BV[1], acc[(IH)*4+fi][1], 0, 0, 0); \
        acc[(IH)*4+fi][2] = __builtin_amdgcn_mfma_f32_16x16x32_bf16(AF[fi], BV[2], acc[(IH)*4+fi][2], 0, 0, 0); \
        acc[(IH)*4+fi][3] = __builtin_amdgcn_mfma_f32_16x16x32_bf16(AF[fi], BV[3], acc[(IH)*4+fi][3], 0, 0, 0); \
    }

    bf16x8 afLo[4], afHi[4], bvE[4], bvO[4];

    // prologue: stage A0,B0,A1,B1,A2,B2 (12 loads, FIFO); gate tile 0; pre-read
    ST_A(0u, 0) ST_B(0u, 0)
    ST_A(32768u, 64)  ST_B(32768u, 64)
    ST_A(65536u, 128) ST_B(65536u, 128)
    asm volatile("s_waitcnt vmcnt(8)" ::: "memory");   // retires A0,B0
    __builtin_amdgcn_s_barrier();
    #pragma unroll
    for (int f = 0; f < 4; ++f) {
        afLo[f] = *(const bf16x8*)(smem + aoff + f * 1024);
        bvE[f]  = *(const bf16x8*)(smem + 16384 + boff + f * 1024);
    }

#define TILE(T, BVC, BVN)                                                                 \
    {                                                                                     \
        const int t_ = (T);                                                               \
        const uint32_t bufc = ((uint32_t)(t_ & 3)) << 15;                                 \
        const uint32_t bufn = ((uint32_t)((t_ + 1) & 3)) << 15;                           \
        const uint32_t bufp = ((uint32_t)((t_ + 3) & 3)) << 15;                           \
        const long kp = (long)(t_ + 3) * 64;                                              \
        const bool sp = (t_ + 3 < nt);                                                    \
        /* ph0: stage A(t+3); barrier; read afHi(t); MFMA fi0-3 */                        \
        if (sp) { ST_A(bufp, kp) }                                                        \
        __builtin_amdgcn_s_barrier();                                                     \
        _Pragma("unroll")                                                                 \
        for (int f = 0; f < 4; ++f)                                                       \
            afHi[f] = *(const bf16x8*)(smem + bufc + aoff + (4 + f) * 1024);              \
        MFMA16(afLo, BVC, 0)                                                              \
        /* ph1: stage B(t+3); counted gate; barrier; read afLo/bv(t+1); MFMA fi4-7 */     \
        if (sp) {                                                                         \
            ST_B(bufp, kp)                                                                \
            asm volatile("s_waitcnt vmcnt(8)" ::: "memory");   /* retires t+1's 4 */      \
        } else if (t_ + 2 < nt) {                                                         \
            asm volatile("s_waitcnt vmcnt(4)" ::: "memory");                              \
        } else if (t_ + 1 < nt) {                                                         \
            asm volatile("s_waitcnt vmcnt(0)" ::: "memory");                              \
        }                                                                                 \
        __builtin_amdgcn_s_barrier();                                                     \
        if (t_ + 1 < nt) {                                                                \
            _Pragma("unroll")                                                             \
            for (int f = 0; f < 4; ++f) {                                                 \
                afLo[f] = *(const bf16x8*)(smem + bufn + aoff + f * 1024);                \
                BVN[f]  = *(const bf16x8*)(smem + bufn + 16384 + boff + f * 1024);        \
            }                                                                             \
        }                                                                                 \
        MFMA16(afHi, BVC, 1)                                                              \
    }

    for (int t = 0; t < nt; t += 2) {
        TILE(t,     bvE, bvO)
        TILE(t + 1, bvO, bvE)
    }
#undef TILE
#undef MFMA16
#undef ST_A
#undef ST_B

    // epilogue: row = row0 + wm*128 + i*16 + (lane>>4)*4 + e ; col = col0 + wn*64 + j*16 + r16
    const int rb = (lane >> 4) * 4;
    #pragma unroll
    for (int i = 0; i < 8; ++i) {
        #pragma unroll
        for (int j = 0; j < 4; ++j) {
            const int cc = col0 + wn * 64 + j * 16 + r16;
            float badd = 0.f;
            if (MODE == 1) badd = bias[cc];
            #pragma unroll
            for (int e = 0; e < 4; ++e) {
                long row = row0 + wm * 128 + i * 16 + rb + e;
                float v = acc[i][j][e];
                if (MODE == 1) {
                    v += badd;
                    v = fmaxf(v, 0.f);
                    v = v * v;
                    ((bf16*)Cout)[row * ldc + cc] = __float2bfloat16(v);
                } else {
                    ((float*)Cout)[row * ldc + cc] = v;
                }
            }
        }
    }
}

// ---------------- glue: per-token gating / tiny einsums ----------------
// In:  g1,g2 [TOK][8][512] f32; Yl[:,0:4096]=x1 raw bf16; Yr[:,4096:8192]=x2 raw bf16
// Out: Yl = [x1*g1s | y12 | g1s]; Yr = [y21 | x2*g2s | g2s]  (all bf16)
#define GPAD 524   // 8-row pad: h-stride hits 8 distinct banks; 524*4%16==0
__global__ __launch_bounds__(256)
void glue(const float* __restrict__ g1, const float* __restrict__ g2,
          bf16* __restrict__ Yl, bf16* __restrict__ Yr)
{
    __shared__ __align__(16) float g1t[8 * GPAD];
    __shared__ __align__(16) float g2t[8 * GPAD];
    __shared__ float g1s[EE], g2s[EE];
    __shared__ float t1s[64], t2s[64];
    __shared__ float t1p[4][64], t2p[4][64];
    __shared__ __align__(16) bf16 x1t[FF], x2t[FF];

    const int t   = blockIdx.x;
    const int tid = threadIdx.x;
    const float* g1p = g1 + (size_t)t * FF;
    const float* g2p = g2 + (size_t)t * FF;
    bf16* ylp = Yl + (size_t)t * KCAT;
    bf16* yrp = Yr + (size_t)t * KCAT;

    #pragma unroll
    for (int c = 0; c < 4; ++c) {
        int idx4 = (c * 256 + tid) * 4;
        float4 v1 = *(const float4*)(g1p + idx4);
        float4 v2 = *(const float4*)(g2p + idx4);
        int h = idx4 >> 9, e = idx4 & 511;
        *(float4*)&g1t[h * GPAD + e] = v1;
        *(float4*)&g2t[h * GPAD + e] = v2;
    }
    #pragma unroll
    for (int c = 0; c < 2; ++c) {
        int idx8 = (c * 256 + tid) * 8;
        *(bf16x8*)&x1t[idx8] = *(const bf16x8*)(ylp + idx8);
        *(bf16x8*)&x2t[idx8] = *(const bf16x8*)(yrp + FF + idx8);
    }
    __syncthreads();

    #pragma unroll
    for (int c = 0; c < 2; ++c) {
        int e = c * 256 + tid;
        float s1 = 0.f, s2 = 0.f;
        #pragma unroll
        for (int h = 0; h < 8; ++h) { s1 += g1t[h * GPAD + e]; s2 += g2t[h * GPAD + e]; }
        g1s[e] = s1; g2s[e] = s2;
    }

    {   // t1[h,m] = sum_e x1[e,m]*g1[h,e] ; t2 likewise. 4-way partials.
        int o = tid & 63;
        int h = o & 7, m = o >> 3;
        int p = tid >> 6;
        float s1 = 0.f, s2 = 0.f;
        #pragma unroll 8
        for (int ii = 0; ii < 128; ++ii) {
            int e = p * 128 + ii;
            float xv1 = __bfloat162float(x1t[e * 8 + m]);
            float xv2 = __bfloat162float(x2t[e * 8 + m]);
            s1 += xv1 * g1t[h * GPAD + e];
            s2 += xv2 * g2t[h * GPAD + e];
        }
        t1p[p][o] = s1; t2p[p][o] = s2;
    }
    __syncthreads();
    if (tid < 64)       t1s[tid] = t1p[0][tid] + t1p[1][tid] + t1p[2][tid] + t1p[3][tid];
    else if (tid < 128) { int o = tid - 64; t2s[o] = t2p[0][o] + t2p[1][o] + t2p[2][o] + t2p[3][o]; }
    __syncthreads();

    #pragma unroll
    for (int c = 0; c < 2; ++c) {
        int f0 = (c * 256 + tid) * 8;
        int e  = f0 >> 3;
        float s1 = g1s[e], s2 = g2s[e];
        bf16x8 xa = *(const bf16x8*)&x1t[f0];
        bf16x8 xb = *(const bf16x8*)&x2t[f0];
        bf16x8 o1, o2;
        #pragma unroll
        for (int u = 0; u < 8; ++u) {
            o1[u] = (__bf16)((float)xa[u] * s1);
            o2[u] = (__bf16)((float)xb[u] * s2);
        }
        *(bf16x8*)(ylp + f0)      = o1;
        *(bf16x8*)(yrp + FF + f0) = o2;
    }
    #pragma unroll
    for (int c = 0; c < 2; ++c) {
        int f0 = (c * 256 + tid) * 8;
        int i  = f0 >> 3;
        bf16x8 o12v, o21v;
        #pragma unroll
        for (int m = 0; m < 8; ++m) {
            float s12 = 0.f, s21 = 0.f;
            #pragma unroll
            for (int h = 0; h < 8; ++h) {
                s12 += t2s[(m << 3) | h] * g1t[h * GPAD + i];
                s21 += t1s[(m << 3) | h] * g2t[h * GPAD + i];
            }
            o12v[m] = (__bf16)s12;
            o21v[m] = (__bf16)s21;
        }
        *(bf16x8*)(ylp + FF + f0) = o12v;
        *(bf16x8*)(yrp + f0)      = o21v;
    }
    {
        int e0 = tid * 2;
        ylp[2 * FF + e0]     = __float2bfloat16(g1s[e0]);
        ylp[2 * FF + e0 + 1] = __float2bfloat16(g1s[e0 + 1]);
        yrp[2 * FF + e0]     = __float2bfloat16(g2s[e0]);
        yrp[2 * FF + e0 + 1] = __float2bfloat16(g2s[e0 + 1]);
    }
}

// ---------------- launch ----------------

extern "C" void kernel_launch(void* const* d_in, const int* in_sizes, int n_in,
                              void* d_out, int out_size, void* d_ws, size_t ws_size,
                              hipStream_t stream) {
    const float* x    = (const float*)d_in[0];
    const float* g1   = (const float*)d_in[1];
    const float* g2   = (const float*)d_in[2];
    const float* u1_w = (const float*)d_in[3];
    const float* u1_b = (const float*)d_in[4];
    const float* u2_w = (const float*)d_in[5];
    const float* u2_b = (const float*)d_in[6];
    const float* v11  = (const float*)d_in[7];
    const float* v12  = (const float*)d_in[8];
    const float* v21  = (const float*)d_in[9];
    const float* v22  = (const float*)d_in[10];
    const float* b1   = (const float*)d_in[11];
    const float* b2   = (const float*)d_in[12];
    float* out = (float*)d_out;

    size_t off = 0;
    char* base = (char*)d_ws;
    auto take = [&](size_t bytes) { void* p = base + off; off += (bytes + 255) & ~(size_t)255; return p; };
    bf16* Xb  = (bf16*)take((size_t)TOK * DD * 2);
    bf16* U1b = (bf16*)take((size_t)FF * DD * 2);
    bf16* U2b = (bf16*)take((size_t)FF * DD * 2);
    bf16* Wl  = (bf16*)take((size_t)HALF * KCAT * 2);
    bf16* Wr  = (bf16*)take((size_t)HALF * KCAT * 2);
    bf16* Yl  = (bf16*)take((size_t)TOK * KCAT * 2);
    bf16* Yr  = (bf16*)take((size_t)TOK * KCAT * 2);

    // prep: x/u casts only (v/b packing rides inside the U-GEMM launch)
    prep_cvt<<<2048, 256, 0, stream>>>(x, u1_w, u2_w, Xb, U1b, U2b);

    // fused U-GEMMs (+256 piggyback pack blocks): x1raw -> Yl[:,0:4096],
    // x2raw -> Yr[:,4096:8192] (relu^2, bf16); v/b -> Wl/Wr
    gemmD<1><<<2 * (TOK / 256) * (FF / 256) + 256, 512, 0, stream>>>(
        Xb, U1b, u1_b, Yl,
        Xb, U2b, u2_b, Yr + FF,
        TOK / 256, FF / 256, DD, KCAT,
        v11, v12, v21, v22, b1, b2, Wl, Wr);

    // gating / tiny einsums
    glue<<<TOK, 256, 0, stream>>>(g1, g2, Yl, Yr);

    // fused V-GEMMs: out[:,0:1024] = Yl @ Wl^T ; out[:,1024:2048] = Yr @ Wr^T  (fp32)
    gemmD<0><<<2 * (TOK / 256) * (HALF / 256), 512, 0, stream>>>(
        Yl, Wl, nullptr, out,
        Yr, Wr, nullptr, out + HALF,
        TOK / 256, HALF / 256, KCAT, DD,
        nullptr, nullptr, nullptr, nullptr, nullptr, nullptr, nullptr, nullptr);
}

// Round 17
// 677.490 us; speedup vs baseline: 1.0044x; 1.0044x over previous
//
#include <hip/hip_runtime.h>
#include <hip/hip_bf16.h>

// MonetMoVDE: B=4 T=2048 D=2048 H=8 E=512 M=8, F=4096, HALF=1024
#define TOK   8192   // B*T
#define DD    2048
#define FF    4096
#define EE    512
#define HALF  1024
#define KCAT  8704   // F + F + E  (concat K for V-GEMMs, 8704 = 136*64)

typedef __bf16 bf16x8 __attribute__((ext_vector_type(8)));
typedef __bf16 bf16x4 __attribute__((ext_vector_type(4)));
typedef float  f32x4  __attribute__((ext_vector_type(4)));
using bf16 = __hip_bfloat16;

#define AS1(p) ((const __attribute__((address_space(1))) void*)(p))
#define AS3(p) ((__attribute__((address_space(3))) void*)(p))

// ---------------- prep: x/u1/u2 f32->bf16 cvt only ----------------
#define PR0 4194304u
#define PR1 6291456u
#define PR2 8388608u
__global__ __launch_bounds__(256)
void prep_cvt(const float* __restrict__ x, const float* __restrict__ u1_w,
              const float* __restrict__ u2_w,
              bf16* __restrict__ Xb, bf16* __restrict__ U1b, bf16* __restrict__ U2b)
{
    const unsigned stride = gridDim.x * blockDim.x;
    for (unsigned i = blockIdx.x * blockDim.x + threadIdx.x; i < PR2; i += stride) {
        const float* src; bf16* dst; unsigned s;
        if (i < PR0)      { s = i;        src = x;    dst = Xb;  }
        else if (i < PR1) { s = i - PR0;  src = u1_w; dst = U1b; }
        else              { s = i - PR1;  src = u2_w; dst = U2b; }
        float4 v = ((const float4*)src)[s];
        bf16x4 o;
        o[0] = (__bf16)v.x; o[1] = (__bf16)v.y; o[2] = (__bf16)v.z; o[3] = (__bf16)v.w;
        ((bf16x4*)dst)[s] = o;
    }
}

// ---------------- GEMM: C[m,n] = sum_k A[m,k] * Bw[n,k] ----------------
// FINAL (r15 = best verified: 677us total, 46-47% MfmaUtil, 0 conflicts).
// 256x256 tile, BK=64, 8 waves (2Mx4N), 16x16x32 MFMA, per-wave C 128x64.
// LDS buffer (64KB) = 4 planes of 16KB: A_k0 @0, A_k1 @16K, B_k0 @32K, B_k1 @48K.
// Plane = 256 rows x 64B, swizzle byte ^= (((row>>1)&3)<<4) - proven zero-conflict.
// Register-pipelined phases: {stage 2 chunk-gloads; [counted vmcnt]; barrier;
// ds_read NEXT phase's frags; MFMA on frags read LAST phase}. Fence-minimized
// barriers (clobber only on vmcnt gates); no setprio (neutral-to-harmful here).
// MODE 1 carries 256 piggyback pack blocks (raw blockIdx >= 2*npg, LDS-free).
// Fused dual-GEMM; MODE 0: fp32 store, MODE 1: relu(z+bias)^2 -> bf16 store.
template<int MODE>
__global__ __launch_bounds__(512, 2)
void gemmP(const bf16* __restrict__ A0, const bf16* __restrict__ B0,
           const float* __restrict__ bias0, void* __restrict__ C0,
           const bf16* __restrict__ A1, const bf16* __restrict__ B1,
           const float* __restrict__ bias1, void* __restrict__ C1,
           int nbm, int nbn, int K, int ldc,
           const float* __restrict__ xv11, const float* __restrict__ xv12,
           const float* __restrict__ xv21, const float* __restrict__ xv22,
           const float* __restrict__ xb1, const float* __restrict__ xb2,
           bf16* __restrict__ xWl, bf16* __restrict__ xWr)
{
    __shared__ __align__(16) char smem[131072];   // 2 x 64KB
    const int tid  = threadIdx.x;
    const int npg  = nbm * nbn;

    if (MODE == 1 && blockIdx.x >= (unsigned)(2 * npg)) {
        // ---- piggyback pack block (no LDS, no barriers) ----
        const unsigned lane_g = (blockIdx.x - 2 * npg) * 512u + tid;   // [0, 131072)
        #pragma unroll 4
        for (int k = 0; k < 32; ++k) {                                  // 4,194,304 float4 slots
            unsigned w = lane_g + (unsigned)k * 131072u;
            const bool left = w < 2097152u;
            unsigned s = left ? w : w - 2097152u;
            unsigned n = s >> 11, j = s & 2047u;
            const float* vs = left ? (j < 1024u ? xv11 : xv12) : (j < 1024u ? xv21 : xv22);
            unsigned jj = (j < 1024u) ? j : (j - 1024u);
            float4 v = *(const float4*)(vs + (size_t)n * FF + jj * 4);
            bf16x4 o;
            o[0] = (__bf16)v.x; o[1] = (__bf16)v.y; o[2] = (__bf16)v.z; o[3] = (__bf16)v.w;
            bf16* wb = left ? xWl : xWr;
            *(bf16x4*)(wb + (size_t)n * KCAT + ((j < 1024u) ? 0 : FF) + jj * 4) = o;
        }
        #pragma unroll 2
        for (int k = 0; k < 8; ++k) {                                   // 1,048,576 bmat scalars
            unsigned w = lane_g + (unsigned)k * 131072u;
            const bool left = w < 524288u;
            unsigned r = left ? w : w - 524288u;
            unsigned n = r >> 9, e = r & 511u;
            const float* bm = left ? xb1 : xb2;
            bf16* wb = left ? xWl : xWr;
            wb[(size_t)n * KCAT + 2 * FF + e] = __float2bfloat16(bm[(size_t)e * HALF + n]);
        }
        return;
    }

    const int lane = tid & 63;
    const int wid  = tid >> 6;
    const int wm = wid >> 2, wn = wid & 3;
    const int r16 = lane & 15, kb = lane >> 4;

    int bid = blockIdx.x;
    {   // bijective XCD swizzle (m204) over the GEMM blocks only
        int nwg = 2 * npg;
        int q = nwg >> 3, r = nwg & 7;
        int xcd = bid & 7, idx = bid >> 3;
        bid = (xcd < r ? xcd * (q + 1) : r * (q + 1) + (xcd - r) * q) + idx;
    }
    const int g   = bid / npg;
    const int lb  = bid - g * npg;
    const int bm = lb / nbn, bn = lb - bm * nbn;

    const bf16*  A    = g ? A1 : A0;
    const bf16*  Bw   = g ? B1 : B0;
    const float* bias = g ? bias1 : bias0;
    char* Cout = (char*)(g ? C1 : C0);

    const long row0 = (long)bm * 256;
    const int  col0 = bn * 256;
    const int  nt   = K >> 6;

    // staging sources (pre-swizzled; involution) + linear LDS dest offset
    const char* gA[2]; const char* gB[2];
    #pragma unroll
    for (int l = 0; l < 2; ++l) {
        const uint32_t S = (uint32_t)(l * 512 + tid) * 16;   // byte slot in 16KB plane
        const int r  = (int)(S >> 6);                        // plane row 0..255
        const int cb = (int)((S & 63) ^ ((uint32_t)((r >> 1) & 3) << 4));
        gA[l] = (const char*)A  + (row0 + r) * (long)K * 2 + cb;
        gB[l] = (const char*)Bw + (long)(col0 + r) * K * 2 + cb;
    }
    const uint32_t ldst = (uint32_t)(tid & ~63) * 16;        // + l*8192 + plane base

    // per-lane read base offsets within a plane (swizzled; proven zero-conflict)
    const uint32_t swz  = ((uint32_t)(r16 >> 1) & 3u) << 4;
    const uint32_t aoff = (uint32_t)((wm * 128 + r16) * 64 + kb * 16) ^ swz;  // +4096 for row-half1, +fi*1024
    const uint32_t boff = (uint32_t)((wn * 64  + r16) * 64 + kb * 16) ^ swz;  // +fj*1024

    f32x4 acc[8][4];
    #pragma unroll
    for (int i = 0; i < 8; ++i)
        #pragma unroll
        for (int j = 0; j < 4; ++j)
            acc[i][j] = (f32x4){0.f, 0.f, 0.f, 0.f};

    // prologue: stage all 4 planes of tile 0 into buf0 (order A_k0,B_k0,A_k1,B_k1)
    __builtin_amdgcn_global_load_lds(AS1(gA[0]),      AS3(smem +     0 + ldst), 16, 0, 0);
    __builtin_amdgcn_global_load_lds(AS1(gA[1]),      AS3(smem +  8192 + ldst), 16, 0, 0);
    __builtin_amdgcn_global_load_lds(AS1(gB[0]),      AS3(smem + 32768 + ldst), 16, 0, 0);
    __builtin_amdgcn_global_load_lds(AS1(gB[1]),      AS3(smem + 40960 + ldst), 16, 0, 0);
    __builtin_amdgcn_global_load_lds(AS1(gA[0] + 64), AS3(smem + 16384 + ldst), 16, 0, 0);
    __builtin_amdgcn_global_load_lds(AS1(gA[1] + 64), AS3(smem + 24576 + ldst), 16, 0, 0);
    __builtin_amdgcn_global_load_lds(AS1(gB[0] + 64), AS3(smem + 49152 + ldst), 16, 0, 0);
    __builtin_amdgcn_global_load_lds(AS1(gB[1] + 64), AS3(smem + 57344 + ldst), 16, 0, 0);
    // gate planes A_k0,B_k0 of tile 0 (first 4 loads), then preload ph0 frags
    asm volatile("s_waitcnt vmcnt(4)" ::: "memory");
    __builtin_amdgcn_s_barrier();

    bf16x8 afA[4], afB[4], bv0[4], bv1[4];
    #pragma unroll
    for (int f = 0; f < 4; ++f) {
        afA[f] = *(const bf16x8*)(smem +     0 + aoff + f * 1024);   // A_k0 h0
        bv0[f] = *(const bf16x8*)(smem + 32768 + boff + f * 1024);   // B_k0
    }

#define MFMA16(AF, BV, IH)                                                              \
    _Pragma("unroll")                                                                   \
    for (int fi = 0; fi < 4; ++fi) {                                                    \
        acc[(IH)*4+fi][0] = __builtin_amdgcn_mfma_f32_16x16x32_bf16(AF[fi], BV[0], acc[(IH)*4+fi][0], 0, 0, 0); \
        acc[(IH)*4+fi][1] = __builtin_amdgcn_mfma_f32_16x16x32_bf16(AF[fi], BV[1], acc[(IH)*4+fi][1], 0, 0, 0); \
        acc[(IH)*4+fi][2] = __builtin_amdgcn_mfma_f32_16x16x32_bf16(AF[fi], BV[2], acc[(IH)*4+fi][2], 0, 0, 0); \
        acc[(IH)*4+fi][3] = __builtin_amdgcn_mfma_f32_16x16x32_bf16(AF[fi], BV[3], acc[(IH)*4+fi][3], 0, 0, 0); \
    }

    for (int t = 0; t < nt; ++t) {
        const char* pb = smem + (t & 1) * 65536;
        char*       pt = smem + ((t + 1) & 1) * 65536;
        const bool  st = (t + 1 < nt);
        const long  koff = (long)(t + 1) * 128;

        // ---- ph0: MFMA(afA,bv0)->acc[0..3]; read afB <- A_k0 h1; stage A_k0(t+1)
        if (st) {
            __builtin_amdgcn_global_load_lds(AS1(gA[0] + koff), AS3(pt +    0 + ldst), 16, 0, 0);
            __builtin_amdgcn_global_load_lds(AS1(gA[1] + koff), AS3(pt + 8192 + ldst), 16, 0, 0);
        }
        __builtin_amdgcn_s_barrier();    // no compiler fence: reads of pb may float
        #pragma unroll
        for (int f = 0; f < 4; ++f)
            afB[f] = *(const bf16x8*)(pb + 4096 + aoff + f * 1024);
        MFMA16(afA, bv0, 0)

        // ---- ph1: MFMA(afB,bv0)->acc[4..7]; read afA <- A_k1 h0, bv1 <- B_k1; stage B_k0(t+1)
        if (st) {
            __builtin_amdgcn_global_load_lds(AS1(gB[0] + koff), AS3(pt + 32768 + ldst), 16, 0, 0);
            __builtin_amdgcn_global_load_lds(AS1(gB[1] + koff), AS3(pt + 40960 + ldst), 16, 0, 0);
            asm volatile("s_waitcnt vmcnt(4)" ::: "memory");   // GATE: retires A_k1(t),B_k1(t)
        } else {
            asm volatile("s_waitcnt vmcnt(0)" ::: "memory");
        }
        __builtin_amdgcn_s_barrier();
        #pragma unroll
        for (int f = 0; f < 4; ++f) {
            afA[f] = *(const bf16x8*)(pb + 16384 + aoff + f * 1024);   // A_k1 h0
            bv1[f] = *(const bf16x8*)(pb + 49152 + boff + f * 1024);   // B_k1
        }
        MFMA16(afB, bv0, 1)

        // ---- ph2: MFMA(afA,bv1)->acc[0..3]; read afB <- A_k1 h1; stage A_k1(t+1)
        if (st) {
            __builtin_amdgcn_global_load_lds(AS1(gA[0] + koff + 64), AS3(pt + 16384 + ldst), 16, 0, 0);
            __builtin_amdgcn_global_load_lds(AS1(gA[1] + koff + 64), AS3(pt + 24576 + ldst), 16, 0, 0);
        }
        __builtin_amdgcn_s_barrier();
        #pragma unroll
        for (int f = 0; f < 4; ++f)
            afB[f] = *(const bf16x8*)(pb + 16384 + 4096 + aoff + f * 1024);
        MFMA16(afA, bv1, 0)

        // ---- ph3: MFMA(afB,bv1)->acc[4..7]; read afA,bv0 <- NEXT tile (from pt); stage B_k1(t+1)
        if (st) {
            __builtin_amdgcn_global_load_lds(AS1(gB[0] + koff + 64), AS3(pt + 49152 + ldst), 16, 0, 0);
            __builtin_amdgcn_global_load_lds(AS1(gB[1] + koff + 64), AS3(pt + 57344 + ldst), 16, 0, 0);
            asm volatile("s_waitcnt vmcnt(4)" ::: "memory");   // GATE: retires A_k0(t+1),B_k0(t+1)
        }
        __builtin_amdgcn_s_barrier();
        if (st) {
            #pragma unroll
            for (int f = 0; f < 4; ++f) {
                afA[f] = *(const bf16x8*)(pt +     0 + aoff + f * 1024);   // A_k0(t+1) h0
                bv0[f] = *(const bf16x8*)(pt + 32768 + boff + f * 1024);   // B_k0(t+1)
            }
        }
        MFMA16(afB, bv1, 1)
    }
#undef MFMA16

    // epilogue: row = row0 + wm*128 + i*16 + (lane>>4)*4 + e ; col = col0 + wn*64 + j*16 + r16
    const int rb = (lane >> 4) * 4;
    #pragma unroll
    for (int i = 0; i < 8; ++i) {
        #pragma unroll
        for (int j = 0; j < 4; ++j) {
            const int cc = col0 + wn * 64 + j * 16 + r16;
            float badd = 0.f;
            if (MODE == 1) badd = bias[cc];
            #pragma unroll
            for (int e = 0; e < 4; ++e) {
                long row = row0 + wm * 128 + i * 16 + rb + e;
                float v = acc[i][j][e];
                if (MODE == 1) {
                    v += badd;
                    v = fmaxf(v, 0.f);
                    v = v * v;
                    ((bf16*)Cout)[row * ldc + cc] = __float2bfloat16(v);
                } else {
                    ((float*)Cout)[row * ldc + cc] = v;
                }
            }
        }
    }
}

// ---------------- glue: per-token gating / tiny einsums ----------------
// In:  g1,g2 [TOK][8][512] f32; Yl[:,0:4096]=x1 raw bf16; Yr[:,4096:8192]=x2 raw bf16
// Out: Yl = [x1*g1s | y12 | g1s]; Yr = [y21 | x2*g2s | g2s]  (all bf16)
#define GPAD 524   // 8-row pad: h-stride hits 8 distinct banks; 524*4%16==0
__global__ __launch_bounds__(256)
void glue(const float* __restrict__ g1, const float* __restrict__ g2,
          bf16* __restrict__ Yl, bf16* __restrict__ Yr)
{
    __shared__ __align__(16) float g1t[8 * GPAD];
    __shared__ __align__(16) float g2t[8 * GPAD];
    __shared__ float g1s[EE], g2s[EE];
    __shared__ float t1s[64], t2s[64];
    __shared__ float t1p[4][64], t2p[4][64];
    __shared__ __align__(16) bf16 x1t[FF], x2t[FF];

    const int t   = blockIdx.x;
    const int tid = threadIdx.x;
    const float* g1p = g1 + (size_t)t * FF;
    const float* g2p = g2 + (size_t)t * FF;
    bf16* ylp = Yl + (size_t)t * KCAT;
    bf16* yrp = Yr + (size_t)t * KCAT;

    #pragma unroll
    for (int c = 0; c < 4; ++c) {
        int idx4 = (c * 256 + tid) * 4;
        float4 v1 = *(const float4*)(g1p + idx4);
        float4 v2 = *(const float4*)(g2p + idx4);
        int h = idx4 >> 9, e = idx4 & 511;
        *(float4*)&g1t[h * GPAD + e] = v1;
        *(float4*)&g2t[h * GPAD + e] = v2;
    }
    #pragma unroll
    for (int c = 0; c < 2; ++c) {
        int idx8 = (c * 256 + tid) * 8;
        *(bf16x8*)&x1t[idx8] = *(const bf16x8*)(ylp + idx8);
        *(bf16x8*)&x2t[idx8] = *(const bf16x8*)(yrp + FF + idx8);
    }
    __syncthreads();

    #pragma unroll
    for (int c = 0; c < 2; ++c) {
        int e = c * 256 + tid;
        float s1 = 0.f, s2 = 0.f;
        #pragma unroll
        for (int h = 0; h < 8; ++h) { s1 += g1t[h * GPAD + e]; s2 += g2t[h * GPAD + e]; }
        g1s[e] = s1; g2s[e] = s2;
    }

    {   // t1[h,m] = sum_e x1[e,m]*g1[h,e] ; t2 likewise. 4-way partials.
        int o = tid & 63;
        int h = o & 7, m = o >> 3;
        int p = tid >> 6;
        float s1 = 0.f, s2 = 0.f;
        #pragma unroll 8
        for (int ii = 0; ii < 128; ++ii) {
            int e = p * 128 + ii;
            float xv1 = __bfloat162float(x1t[e * 8 + m]);
            float xv2 = __bfloat162float(x2t[e * 8 + m]);
            s1 += xv1 * g1t[h * GPAD + e];
            s2 += xv2 * g2t[h * GPAD + e];
        }
        t1p[p][o] = s1; t2p[p][o] = s2;
    }
    __syncthreads();
    if (tid < 64)       t1s[tid] = t1p[0][tid] + t1p[1][tid] + t1p[2][tid] + t1p[3][tid];
    else if (tid < 128) { int o = tid - 64; t2s[o] = t2p[0][o] + t2p[1][o] + t2p[2][o] + t2p[3][o]; }
    __syncthreads();

    #pragma unroll
    for (int c = 0; c < 2; ++c) {
        int f0 = (c * 256 + tid) * 8;
        int e  = f0 >> 3;
        float s1 = g1s[e], s2 = g2s[e];
        bf16x8 xa = *(const bf16x8*)&x1t[f0];
        bf16x8 xb = *(const bf16x8*)&x2t[f0];
        bf16x8 o1, o2;
        #pragma unroll
        for (int u = 0; u < 8; ++u) {
            o1[u] = (__bf16)((float)xa[u] * s1);
            o2[u] = (__bf16)((float)xb[u] * s2);
        }
        *(bf16x8*)(ylp + f0)      = o1;
        *(bf16x8*)(yrp + FF + f0) = o2;
    }
    #pragma unroll
    for (int c = 0; c < 2; ++c) {
        int f0 = (c * 256 + tid) * 8;
        int i  = f0 >> 3;
        bf16x8 o12v, o21v;
        #pragma unroll
        for (int m = 0; m < 8; ++m) {
            float s12 = 0.f, s21 = 0.f;
            #pragma unroll
            for (int h = 0; h < 8; ++h) {
                s12 += t2s[(m << 3) | h] * g1t[h * GPAD + i];
                s21 += t1s[(m << 3) | h] * g2t[h * GPAD + i];
            }
            o12v[m] = (__bf16)s12;
            o21v[m] = (__bf16)s21;
        }
        *(bf16x8*)(ylp + FF + f0) = o12v;
        *(bf16x8*)(yrp + f0)      = o21v;
    }
    {
        int e0 = tid * 2;
        ylp[2 * FF + e0]     = __float2bfloat16(g1s[e0]);
        ylp[2 * FF + e0 + 1] = __float2bfloat16(g1s[e0 + 1]);
        yrp[2 * FF + e0]     = __float2bfloat16(g2s[e0]);
        yrp[2 * FF + e0 + 1] = __float2bfloat16(g2s[e0 + 1]);
    }
}

// ---------------- launch ----------------

extern "C" void kernel_launch(void* const* d_in, const int* in_sizes, int n_in,
                              void* d_out, int out_size, void* d_ws, size_t ws_size,
                              hipStream_t stream) {
    const float* x    = (const float*)d_in[0];
    const float* g1   = (const float*)d_in[1];
    const float* g2   = (const float*)d_in[2];
    const float* u1_w = (const float*)d_in[3];
    const float* u1_b = (const float*)d_in[4];
    const float* u2_w = (const float*)d_in[5];
    const float* u2_b = (const float*)d_in[6];
    const float* v11  = (const float*)d_in[7];
    const float* v12  = (const float*)d_in[8];
    const float* v21  = (const float*)d_in[9];
    const float* v22  = (const float*)d_in[10];
    const float* b1   = (const float*)d_in[11];
    const float* b2   = (const float*)d_in[12];
    float* out = (float*)d_out;

    size_t off = 0;
    char* base = (char*)d_ws;
    auto take = [&](size_t bytes) { void* p = base + off; off += (bytes + 255) & ~(size_t)255; return p; };
    bf16* Xb  = (bf16*)take((size_t)TOK * DD * 2);
    bf16* U1b = (bf16*)take((size_t)FF * DD * 2);
    bf16* U2b = (bf16*)take((size_t)FF * DD * 2);
    bf16* Wl  = (bf16*)take((size_t)HALF * KCAT * 2);
    bf16* Wr  = (bf16*)take((size_t)HALF * KCAT * 2);
    bf16* Yl  = (bf16*)take((size_t)TOK * KCAT * 2);
    bf16* Yr  = (bf16*)take((size_t)TOK * KCAT * 2);

    // prep: x/u casts only (v/b packing rides inside the U-GEMM launch)
    prep_cvt<<<2048, 256, 0, stream>>>(x, u1_w, u2_w, Xb, U1b, U2b);

    // fused U-GEMMs (+256 piggyback pack blocks): x1raw -> Yl[:,0:4096],
    // x2raw -> Yr[:,4096:8192] (relu^2, bf16); v/b -> Wl/Wr
    gemmP<1><<<2 * (TOK / 256) * (FF / 256) + 256, 512, 0, stream>>>(
        Xb, U1b, u1_b, Yl,
        Xb, U2b, u2_b, Yr + FF,
        TOK / 256, FF / 256, DD, KCAT,
        v11, v12, v21, v22, b1, b2, Wl, Wr);

    // gating / tiny einsums
    glue<<<TOK, 256, 0, stream>>>(g1, g2, Yl, Yr);

    // fused V-GEMMs: out[:,0:1024] = Yl @ Wl^T ; out[:,1024:2048] = Yr @ Wr^T  (fp32)
    gemmP<0><<<2 * (TOK / 256) * (HALF / 256), 512, 0, stream>>>(
        Yl, Wl, nullptr, out,
        Yr, Wr, nullptr, out + HALF,
        TOK / 256, HALF / 256, KCAT, DD,
        nullptr, nullptr, nullptr, nullptr, nullptr, nullptr, nullptr, nullptr);
}